// Round 18
// baseline (153.705 us; speedup 1.0000x reference)
//
#include <hip/hip_runtime.h>

#define F_IN  384
#define EPB   4096   // edges per block, pass 1
#define NBINS 256    // dsts per coarse bucket
#define BCAP  10240  // eidx region stride per bucket (avg 8163, ~20-sigma margin)
#define SDS   208    // segdesc row stride (u16 entries), >= NBK+1

typedef __attribute__((ext_vector_type(8))) short short8v;   // bf16x8 MFMA fragment
typedef __attribute__((ext_vector_type(4))) float f32x4;     // MFMA accumulator

// bf16 helpers (RNE), no header-type dependence
__device__ __forceinline__ unsigned short f2bf(float f) {
    unsigned u = __float_as_uint(f);
    return (unsigned short)((u + 0x7FFFu + ((u >> 16) & 1u)) >> 16);
}
__device__ __forceinline__ float bflo(unsigned u) { return __uint_as_float(u << 16); }
__device__ __forceinline__ float bfhi(unsigned u) { return __uint_as_float(u & 0xFFFF0000u); }

// ---------------- pass 1: coarse bucket partition (dst>>8), atomic-free ----------------

__launch_bounds__(256)
__global__ void k_p1(const int* __restrict__ ei, int E, int NBK,
                     unsigned* __restrict__ packed, unsigned short* __restrict__ segdesc) {
    __shared__ unsigned sin[EPB];
    __shared__ unsigned sout[EPB];
    __shared__ int hist[257], cur[256], excl[257];
    const int t = threadIdx.x;
    const int e0 = blockIdx.x * EPB;
    const int cnt = min(EPB, E - e0);

    if (t < 256) { hist[t] = 0; cur[t] = 0; }
    if (t == 0) hist[256] = 0;
    __syncthreads();

    for (int i = t; i < cnt; i += 256) {
        int s = ei[e0 + i];
        int d = ei[E + e0 + i];
        sin[i] = ((unsigned)d << 16) | (unsigned)s;   // N < 65536 for both
        atomicAdd(&hist[d >> 8], 1);
    }
    __syncthreads();

    if (t < 64) {  // wave 0: exclusive scan of hist[0..NBK)
        int carry = 0;
        for (int c = 0; c * 64 < NBK; ++c) {
            int idx = c * 64 + t;
            int v = (idx < NBK) ? hist[idx] : 0;
            int x = v;
#pragma unroll
            for (int d = 1; d < 64; d <<= 1) { int y = __shfl_up(x, d, 64); if (t >= d) x += y; }
            if (idx < NBK) excl[idx] = carry + x - v;
            carry += __shfl(x, 63, 64);
        }
        if (t == 0) excl[NBK] = carry;   // == cnt
    }
    __syncthreads();

    for (int i = t; i < cnt; i += 256) {
        unsigned v = sin[i];
        int b = v >> 24;                 // dst >> 8
        int pos = excl[b] + atomicAdd(&cur[b], 1);   // LDS atomic (fast)
        sout[pos] = v;
    }
    __syncthreads();

    for (int i = t; i < cnt; i += 256) packed[(size_t)e0 + i] = sout[i];   // coalesced
    for (int i = t; i <= NBK; i += 256) segdesc[(size_t)blockIdx.x * SDS + i] = (unsigned short)excl[i];
}

// ---------------- pass 2: per-bucket exact CSR (rpB/rpE/dinv/eidx), all in LDS ----------------

__launch_bounds__(256)
__global__ void k_p2(const unsigned* __restrict__ packed, const unsigned short* __restrict__ segdesc,
                     int NB1, unsigned short* __restrict__ eidx,
                     int* __restrict__ rpB, int* __restrict__ rpE,
                     float* __restrict__ dinv, int N) {
    __shared__ unsigned ev[BCAP];
    __shared__ unsigned short se[BCAP];
    __shared__ int lenS[512], offS[513], srcS[512];
    __shared__ int hist[NBINS], cur[NBINS], excl[NBINS + 1];
    const int t = threadIdx.x;
    const int b = blockIdx.x;

    if (t < NBINS) { hist[t] = 0; cur[t] = 0; }
    for (int blk = t; blk < NB1; blk += 256) {
        int s0 = segdesc[(size_t)blk * SDS + b];
        int s1 = segdesc[(size_t)blk * SDS + b + 1];
        lenS[blk] = s1 - s0;
        srcS[blk] = s0;
    }
    __syncthreads();

    if (t < 64) {  // wave 0: exclusive scan of lenS[0..NB1)
        int carry = 0;
        for (int c = 0; c * 64 < NB1; ++c) {
            int idx = c * 64 + t;
            int v = (idx < NB1) ? lenS[idx] : 0;
            int x = v;
#pragma unroll
            for (int d = 1; d < 64; d <<= 1) { int y = __shfl_up(x, d, 64); if (t >= d) x += y; }
            if (idx < NB1) offS[idx] = carry + x - v;
            carry += __shfl(x, 63, 64);
        }
        if (t == 0) offS[NB1 < 512 ? NB1 : 512] = carry;
    }
    __syncthreads();
    const int total = min(offS[NB1 < 512 ? NB1 : 512], BCAP);

    // gather this bucket's segments into LDS: one thread per source block (256
    // independent load streams; srcS/lenS/offS from LDS so no global dep chain)
    for (int blk = t; blk < NB1; blk += 256) {
        int l = lenS[blk], o = offS[blk];
        if (o + l > BCAP) l = max(0, BCAP - o);
        const unsigned* sp = packed + (size_t)blk * EPB + srcS[blk];
        for (int j = 0; j < l; ++j) ev[o + j] = sp[j];
    }
    __syncthreads();

    for (int i = t; i < total; i += 256) atomicAdd(&hist[(ev[i] >> 16) & 0xFF], 1);
    __syncthreads();

    if (t < 64) {  // wave 0: exclusive scan of hist[0..256)
        int carry = 0;
#pragma unroll
        for (int c = 0; c < 4; ++c) {
            int idx = c * 64 + t;
            int v = hist[idx];
            int x = v;
#pragma unroll
            for (int d = 1; d < 64; d <<= 1) { int y = __shfl_up(x, d, 64); if (t >= d) x += y; }
            excl[idx] = carry + x - v;
            carry += __shfl(x, 63, 64);
        }
        if (t == 0) excl[NBINS] = carry;
    }
    __syncthreads();

    if (t < NBINS) {
        int d = b * NBINS + t;
        if (d < N) {
            int c = hist[t];
            int base = b * BCAP + excl[t];
            rpB[d] = base;
            rpE[d] = base + c;
            dinv[d] = rsqrtf((float)(c + 1));   // +1 self-loop
        }
    }
    for (int i = t; i < total; i += 256) {
        unsigned v = ev[i];
        int l = (v >> 16) & 0xFF;
        int p = excl[l] + atomicAdd(&cur[l], 1);
        se[p] = (unsigned short)(v & 0xFFFF);
    }
    __syncthreads();
    for (int i = t; i < total; i += 256) eidx[(size_t)b * BCAP + i] = se[i];
}

// ---------------- weight pre-transpose: w1t[col][k] bf16 (64x384), w3t[col][k] bf16 (384x32) ----------------

__global__ void k_wt(const float* __restrict__ W1, const float* __restrict__ W3,
                     unsigned short* __restrict__ w1t, unsigned short* __restrict__ w3t) {
    int idx = blockIdx.x * 256 + threadIdx.x;
    if (idx < 384 * 64) {                 // W1: [k=384][col=64] -> w1t[col][k]
        int k = idx >> 6, col = idx & 63;
        w1t[(size_t)col * 384 + k] = f2bf(W1[idx]);
    }
    int j = idx - 384 * 64;
    if (j >= 0 && j < 384 * 32) {         // W3 cols 0..383: [k=32][col=385] -> w3t[col][k]
        int col = j >> 5, k = j & 31;
        w3t[(size_t)col * 32 + k] = f2bf(W3[(size_t)k * 385 + col]);
    }
}

// ---------------- GEMM1 (MFMA, global_load_lds): m1p = bf16((x @ W1) * dinv) ----------------
// 32 rows/block. Full A-panel (32x384 fp32, 48 KB) staged in ONE phase via 48
// wave-level global_load_lds (12 per wave, all independent), then ONE barrier,
// then pure ds_read_b128 + cvt + MFMA. LDS dest is HW-linear; bank conflicts
// avoided by XOR-swizzling the SOURCE global address (rule #21) and applying
// the same XOR on the read side: byte ^= ((row & 7) << 4).

__launch_bounds__(256)
__global__ void k_gemm1(const float* __restrict__ x, const unsigned short* __restrict__ w1t,
                        const float* __restrict__ dinv,
                        unsigned short* __restrict__ m1p, int N) {
    __shared__ __align__(16) unsigned char xb[32 * 1536];   // 48 KB fp32 panel
    const int t    = threadIdx.x;
    const int lane = t & 63;
    const int wv   = t >> 6;        // wave id 0..3 -> col strip
    const int lr   = lane & 15;     // fragment row (A) / col (B)
    const int kg   = lane >> 4;     // k-group 0..3
    const int row0 = blockIdx.x * 32;
    const int col  = (wv << 4) + lr;

    // preload all 12 B fragments (independent 16B loads from L2-resident w1t)
    short8v bf[12];
    const unsigned short* wcol = w1t + (size_t)col * 384 + (kg << 3);
#pragma unroll
    for (int c = 0; c < 12; c++)
        bf[c] = *reinterpret_cast<const short8v*>(&wcol[c * 32]);

    // stage: wave wv issues 12 DMA, segment seg covers LDS [seg*1024, +1024)
#pragma unroll
    for (int d = 0; d < 12; d++) {
        int seg = wv * 12 + d;
        int o   = seg * 1024 + lane * 16;        // this lane's linear LDS dest
        int r   = o / 1536;                      // panel row (XOR keeps row: 1536=0x600, mask<0x80)
        int rem = (o % 1536) ^ ((r & 7) << 4);   // inverse-swizzled byte within row
        int row = row0 + r;
        const float* src = (row < N)
            ? (const float*)((const char*)x + (size_t)row * 1536 + rem)
            : x;   // OOB lanes load safe garbage; those rows are masked at store
        __builtin_amdgcn_global_load_lds(
            (const __attribute__((address_space(1))) unsigned int*)src,
            (__attribute__((address_space(3))) unsigned int*)(xb + seg * 1024),
            16, 0, 0);
    }
    __syncthreads();

    f32x4 acc0 = (f32x4){0.f, 0.f, 0.f, 0.f};
    f32x4 acc1 = (f32x4){0.f, 0.f, 0.f, 0.f};
    const int m = (lr & 7) << 4;   // same mask for row lr and row 16+lr

#pragma unroll
    for (int c = 0; c < 12; c++) {
        int bA = lr * 1536 + c * 128 + (kg << 5);
        int bB = (16 + lr) * 1536 + c * 128 + (kg << 5);
        float4 fa1 = *reinterpret_cast<const float4*>(xb + ((bA)      ^ m));
        float4 fa2 = *reinterpret_cast<const float4*>(xb + ((bA + 16) ^ m));
        float4 fb1 = *reinterpret_cast<const float4*>(xb + ((bB)      ^ m));
        float4 fb2 = *reinterpret_cast<const float4*>(xb + ((bB + 16) ^ m));
        short8v a0, a1;
        a0[0] = (short)f2bf(fa1.x); a0[1] = (short)f2bf(fa1.y);
        a0[2] = (short)f2bf(fa1.z); a0[3] = (short)f2bf(fa1.w);
        a0[4] = (short)f2bf(fa2.x); a0[5] = (short)f2bf(fa2.y);
        a0[6] = (short)f2bf(fa2.z); a0[7] = (short)f2bf(fa2.w);
        a1[0] = (short)f2bf(fb1.x); a1[1] = (short)f2bf(fb1.y);
        a1[2] = (short)f2bf(fb1.z); a1[3] = (short)f2bf(fb1.w);
        a1[4] = (short)f2bf(fb2.x); a1[5] = (short)f2bf(fb2.y);
        a1[6] = (short)f2bf(fb2.z); a1[7] = (short)f2bf(fb2.w);
        acc0 = __builtin_amdgcn_mfma_f32_16x16x32_bf16(a0, bf[c], acc0, 0, 0, 0);
        acc1 = __builtin_amdgcn_mfma_f32_16x16x32_bf16(a1, bf[c], acc1, 0, 0, 0);
    }

    const size_t hbase = (size_t)(col >> 5) * ((size_t)N * 32) + (col & 31);
#pragma unroll
    for (int i = 0; i < 4; i++) {
        int rowA = row0 + (kg << 2) + i;
        if (rowA < N) m1p[hbase + (size_t)rowA * 32] = f2bf(acc0[i] * dinv[rowA]);
        int rowB = row0 + 16 + (kg << 2) + i;
        if (rowB < N) m1p[hbase + (size_t)rowB * 32] = f2bf(acc1[i] * dinv[rowB]);
    }
}

// ---------------- gather layer-1, one feature-half: m1h half = bf16(relu(s*agg + b1h)) ----------------
// msg = [N][16] u32 half-array (3.2 MB, L2-resident). 16 lanes per node, unroll 8.

__launch_bounds__(256)
__global__ void k_g64half(const int* __restrict__ rpB, const int* __restrict__ rpE,
                          const unsigned short* __restrict__ eidx,
                          const unsigned* __restrict__ msg,   // [N][16] packed bf16 pairs (half h)
                          const float* __restrict__ b1h,      // b1 + 32*h
                          const float* __restrict__ dinv,
                          unsigned* __restrict__ m1h,         // [N][32] u32; we write cols houtoff..houtoff+15
                          int houtoff, int N) {
    int w = blockIdx.x * 16 + (threadIdx.x >> 4);
    if (w >= N) return;
    int f = threadIdx.x & 15;
    int i = rpB[w], e = rpE[w];
    unsigned u = msg[(size_t)w * 16 + f];           // self-loop
    float l0 = bflo(u), h0 = bfhi(u);
    float l1 = 0.f, h1 = 0.f, l2 = 0.f, h2 = 0.f, l3 = 0.f, h3 = 0.f;
    float l4 = 0.f, h4 = 0.f, l5 = 0.f, h5 = 0.f, l6 = 0.f, h6 = 0.f, l7 = 0.f, h7 = 0.f;
    for (; i + 8 <= e; i += 8) {
        unsigned u0 = msg[(size_t)eidx[i]     * 16 + f];
        unsigned u1 = msg[(size_t)eidx[i + 1] * 16 + f];
        unsigned u2 = msg[(size_t)eidx[i + 2] * 16 + f];
        unsigned u3 = msg[(size_t)eidx[i + 3] * 16 + f];
        unsigned u4 = msg[(size_t)eidx[i + 4] * 16 + f];
        unsigned u5 = msg[(size_t)eidx[i + 5] * 16 + f];
        unsigned u6 = msg[(size_t)eidx[i + 6] * 16 + f];
        unsigned u7 = msg[(size_t)eidx[i + 7] * 16 + f];
        l0 += bflo(u0); h0 += bfhi(u0);  l1 += bflo(u1); h1 += bfhi(u1);
        l2 += bflo(u2); h2 += bfhi(u2);  l3 += bflo(u3); h3 += bfhi(u3);
        l4 += bflo(u4); h4 += bfhi(u4);  l5 += bflo(u5); h5 += bfhi(u5);
        l6 += bflo(u6); h6 += bfhi(u6);  l7 += bflo(u7); h7 += bfhi(u7);
    }
    for (; i + 4 <= e; i += 4) {
        unsigned u0 = msg[(size_t)eidx[i]     * 16 + f];
        unsigned u1 = msg[(size_t)eidx[i + 1] * 16 + f];
        unsigned u2 = msg[(size_t)eidx[i + 2] * 16 + f];
        unsigned u3 = msg[(size_t)eidx[i + 3] * 16 + f];
        l0 += bflo(u0); h0 += bfhi(u0);  l1 += bflo(u1); h1 += bfhi(u1);
        l2 += bflo(u2); h2 += bfhi(u2);  l3 += bflo(u3); h3 += bfhi(u3);
    }
    for (; i < e; i++) {
        unsigned u0 = msg[(size_t)eidx[i] * 16 + f];
        l0 += bflo(u0); h0 += bfhi(u0);
    }
    float suml = ((l0 + l1) + (l2 + l3)) + ((l4 + l5) + (l6 + l7));
    float sumh = ((h0 + h1) + (h2 + h3)) + ((h4 + h5) + (h6 + h7));
    float s = dinv[w];
    float hl = fmaxf(suml * s + b1h[(f << 1)], 0.f);
    float hh = fmaxf(sumh * s + b1h[(f << 1) + 1], 0.f);
    m1h[(size_t)w * 32 + houtoff + f] = (unsigned)f2bf(hl) | ((unsigned)f2bf(hh) << 16);
}

// ---------------- CSR gather, 32 bf16 features: 16 lanes per node, unroll 8 ----------------
// bias != null: fused mid-layer epilogue h' = bf16(relu(r*s + b) * s) packed to outp.
// bias == null (final pass): write g = bf16(r*s) packed (A-operand-ready for k_out)
//   AND compute out[:,384] = g . W3[:,384] + b3[384] via 16-lane shfl reduce.

__launch_bounds__(256)
__global__ void k_gather32h(const int* __restrict__ rpB, const int* __restrict__ rpE,
                            const unsigned short* __restrict__ eidx,
                            const unsigned* __restrict__ msg,   // [N][16] packed bf16 pairs
                            void* __restrict__ outp, int N,
                            const float* __restrict__ bias, const float* __restrict__ dinv,
                            const float* __restrict__ W3, const float* __restrict__ b3,
                            float* __restrict__ out) {
    int w = blockIdx.x * 16 + (threadIdx.x >> 4);
    if (w >= N) return;
    int f = threadIdx.x & 15;
    int i = rpB[w], e = rpE[w];
    unsigned u = msg[(size_t)w * 16 + f];           // self-loop
    float l0 = bflo(u), h0 = bfhi(u);
    float l1 = 0.f, h1 = 0.f, l2 = 0.f, h2 = 0.f, l3 = 0.f, h3 = 0.f;
    float l4 = 0.f, h4 = 0.f, l5 = 0.f, h5 = 0.f, l6 = 0.f, h6 = 0.f, l7 = 0.f, h7 = 0.f;
    for (; i + 8 <= e; i += 8) {
        unsigned u0 = msg[(size_t)eidx[i]     * 16 + f];
        unsigned u1 = msg[(size_t)eidx[i + 1] * 16 + f];
        unsigned u2 = msg[(size_t)eidx[i + 2] * 16 + f];
        unsigned u3 = msg[(size_t)eidx[i + 3] * 16 + f];
        unsigned u4 = msg[(size_t)eidx[i + 4] * 16 + f];
        unsigned u5 = msg[(size_t)eidx[i + 5] * 16 + f];
        unsigned u6 = msg[(size_t)eidx[i + 6] * 16 + f];
        unsigned u7 = msg[(size_t)eidx[i + 7] * 16 + f];
        l0 += bflo(u0); h0 += bfhi(u0);  l1 += bflo(u1); h1 += bfhi(u1);
        l2 += bflo(u2); h2 += bfhi(u2);  l3 += bflo(u3); h3 += bfhi(u3);
        l4 += bflo(u4); h4 += bfhi(u4);  l5 += bflo(u5); h5 += bfhi(u5);
        l6 += bflo(u6); h6 += bfhi(u6);  l7 += bflo(u7); h7 += bfhi(u7);
    }
    for (; i + 4 <= e; i += 4) {
        unsigned u0 = msg[(size_t)eidx[i]     * 16 + f];
        unsigned u1 = msg[(size_t)eidx[i + 1] * 16 + f];
        unsigned u2 = msg[(size_t)eidx[i + 2] * 16 + f];
        unsigned u3 = msg[(size_t)eidx[i + 3] * 16 + f];
        l0 += bflo(u0); h0 += bfhi(u0);  l1 += bflo(u1); h1 += bfhi(u1);
        l2 += bflo(u2); h2 += bfhi(u2);  l3 += bflo(u3); h3 += bfhi(u3);
    }
    for (; i < e; i++) {
        unsigned u0 = msg[(size_t)eidx[i] * 16 + f];
        l0 += bflo(u0); h0 += bfhi(u0);
    }
    float rl = ((l0 + l1) + (l2 + l3)) + ((l4 + l5) + (l6 + l7));
    float rh = ((h0 + h1) + (h2 + h3)) + ((h4 + h5) + (h6 + h7));
    float s = dinv[w];
    if (bias) {
        rl = fmaxf(rl * s + bias[(f << 1)], 0.f) * s;
        rh = fmaxf(rh * s + bias[(f << 1) + 1], 0.f) * s;
        ((unsigned*)outp)[(size_t)w * 16 + f] = (unsigned)f2bf(rl) | ((unsigned)f2bf(rh) << 16);
    } else {
        float gl = rl * s, gh = rh * s;
        ((unsigned*)outp)[(size_t)w * 16 + f] = (unsigned)f2bf(gl) | ((unsigned)f2bf(gh) << 16);
        // fused column 384 of the output GEMM (f32 precision)
        float p = gl * W3[(size_t)(2 * f) * 385 + 384] + gh * W3[(size_t)(2 * f + 1) * 385 + 384];
#pragma unroll
        for (int m = 8; m >= 1; m >>= 1) p += __shfl_xor(p, m, 64);   // 16-lane group reduce
        if (f == 0) out[(size_t)w * 385 + 384] = p + b3[384];
    }
}

// ---------------- layer2 (MFMA, LDS-free): m2p = bf16((m1h @ W2) * s) ----------------

__launch_bounds__(256)
__global__ void k_layer2(const unsigned* __restrict__ m1h, const float* __restrict__ W2,
                         const float* __restrict__ dinv,
                         unsigned short* __restrict__ m2p, int N) {
    const int t    = threadIdx.x;
    const int lane = t & 63;
    const int wv   = t >> 6;
    const int lr   = lane & 15;
    const int kg   = lane >> 4;
    const int row0 = blockIdx.x * 64 + (wv << 4);

    short8v b00, b01, b10, b11;   // b[khalf][colstrip]
#pragma unroll
    for (int j = 0; j < 8; j++) {
        int k = (kg << 3) + j;
        b00[j] = (short)f2bf(W2[(size_t)k * 32 + lr]);
        b01[j] = (short)f2bf(W2[(size_t)k * 32 + 16 + lr]);
        b10[j] = (short)f2bf(W2[(size_t)(32 + k) * 32 + lr]);
        b11[j] = (short)f2bf(W2[(size_t)(32 + k) * 32 + 16 + lr]);
    }

    int arow = row0 + lr;
    short8v a0 = (short8v){0, 0, 0, 0, 0, 0, 0, 0};
    short8v a1 = (short8v){0, 0, 0, 0, 0, 0, 0, 0};
    if (arow < N) {
        a0 = *reinterpret_cast<const short8v*>(&m1h[(size_t)arow * 32 + (kg << 2)]);        // k 0..31
        a1 = *reinterpret_cast<const short8v*>(&m1h[(size_t)arow * 32 + 16 + (kg << 2)]);   // k 32..63
    }

    f32x4 accA = (f32x4){0.f, 0.f, 0.f, 0.f};
    f32x4 accB = (f32x4){0.f, 0.f, 0.f, 0.f};
    accA = __builtin_amdgcn_mfma_f32_16x16x32_bf16(a0, b00, accA, 0, 0, 0);
    accA = __builtin_amdgcn_mfma_f32_16x16x32_bf16(a1, b10, accA, 0, 0, 0);
    accB = __builtin_amdgcn_mfma_f32_16x16x32_bf16(a0, b01, accB, 0, 0, 0);
    accB = __builtin_amdgcn_mfma_f32_16x16x32_bf16(a1, b11, accB, 0, 0, 0);

#pragma unroll
    for (int i = 0; i < 4; i++) {
        int row = row0 + (kg << 2) + i;
        if (row < N) {
            float s = dinv[row];
            m2p[(size_t)row * 32 + lr]      = f2bf(accA[i] * s);
            m2p[(size_t)row * 32 + 16 + lr] = f2bf(accB[i] * s);
        }
    }
}

// ---------------- out GEMM (MFMA, LDS-free): out[:, 0:384] = g @ W3 + b3; sigmoid col 0 ----------------
// B fragment: single 16B load from bf16-transposed w3t (L2-resident).

__launch_bounds__(256)
__global__ void k_out(const unsigned* __restrict__ gbf, const unsigned short* __restrict__ w3t,
                      const float* __restrict__ b3, float* __restrict__ out, int N) {
    const int t    = threadIdx.x;
    const int lane = t & 63;
    const int wv   = t >> 6;
    const int lr   = lane & 15;
    const int kg   = lane >> 4;
    const int row0 = blockIdx.x * 64;
    const int col  = blockIdx.y * 64 + (wv << 4) + lr;   // always < 384

    short8v bfrag = *reinterpret_cast<const short8v*>(&w3t[(size_t)col * 32 + (kg << 3)]);
    const float bias = b3[col];

#pragma unroll
    for (int rb = 0; rb < 4; rb++) {
        int arow = row0 + (rb << 4) + lr;
        short8v afrag = (short8v){0, 0, 0, 0, 0, 0, 0, 0};
        if (arow < N)
            afrag = *reinterpret_cast<const short8v*>(&gbf[(size_t)arow * 16 + (kg << 2)]);
        f32x4 acc = (f32x4){0.f, 0.f, 0.f, 0.f};
        acc = __builtin_amdgcn_mfma_f32_16x16x32_bf16(afrag, bfrag, acc, 0, 0, 0);
#pragma unroll
        for (int i = 0; i < 4; i++) {
            int row = row0 + (rb << 4) + (kg << 2) + i;
            if (row < N) {
                float v = acc[i] + bias;
                if (col == 0) v = 1.0f / (1.0f + expf(-v));
                out[(size_t)row * 385 + col] = v;
            }
        }
    }
}

extern "C" void kernel_launch(void* const* d_in, const int* in_sizes, int n_in,
                              void* d_out, int out_size, void* d_ws, size_t ws_size,
                              hipStream_t stream) {
    const float* x  = (const float*)d_in[0];
    const int*   ei = (const int*)d_in[1];
    const float* W1 = (const float*)d_in[2];
    const float* b1 = (const float*)d_in[3];
    const float* W2 = (const float*)d_in[4];
    const float* b2 = (const float*)d_in[5];
    const float* W3 = (const float*)d_in[6];
    const float* b3 = (const float*)d_in[7];
    float* out = (float*)d_out;

    const int N = in_sizes[0] / F_IN;   // 50000
    const int E = in_sizes[1] / 2;      // 1600000
    const int NB1 = (E + EPB - 1) / EPB;       // 391 pass-1 blocks
    const int NBK = (N + NBINS - 1) / NBINS;   // 196 coarse buckets

    float* ws   = (float*)d_ws;
    float* dinv = ws;
    float* bufA = ws + N;
    float* bufB = bufA + (size_t)64 * N;
    int*   rpB  = (int*)(bufB + (size_t)64 * N);
    int*   rpE  = rpB + N;
    unsigned short* eidx    = (unsigned short*)(rpE + N);
    unsigned short* segdesc = eidx + (size_t)NBK * BCAP;
    unsigned short* w1t     = segdesc + (size_t)NB1 * SDS;   // [64][384] bf16 (16B-aligned)
    unsigned short* w3t     = w1t + (size_t)64 * 384;        // [384][32] bf16

    unsigned* packed = (unsigned*)bufA;              // E u32; dead after k_p2
    unsigned short* m1p = (unsigned short*)bufA;     // [2][N][32] bf16 halves (6.4 MB total)
    unsigned* m1h = (unsigned*)bufB;                 // [N][32] u32 packed bf16 h1
    unsigned short* m2p = (unsigned short*)bufA;     // [N,32] bf16 (m1p dead)
    unsigned short* h2p = (unsigned short*)bufB;     // [N,32] bf16 (m1h dead)
    unsigned* gbf = (unsigned*)(bufA + (size_t)32 * N);  // [N,16] u32 packed bf16 g (no overlap with m2p)

    k_p1<<<NB1, 256, 0, stream>>>(ei, E, NBK, packed, segdesc);
    k_p2<<<NBK, 256, 0, stream>>>(packed, segdesc, NB1, eidx, rpB, rpE, dinv, N);
    k_wt<<<(384 * 64 + 384 * 32 + 255) / 256, 256, 0, stream>>>(W1, W3, w1t, w3t);

    k_gemm1  <<<(N + 31) / 32, 256, 0, stream>>>(x, w1t, dinv, m1p, N);
    // layer-1 gather: two feature-half passes, each msg half (3.2 MB) is L2-resident
    k_g64half<<<(N + 15) / 16, 256, 0, stream>>>(rpB, rpE, eidx,
                                                 (const unsigned*)m1p,                       b1,      dinv, m1h,  0, N);
    k_g64half<<<(N + 15) / 16, 256, 0, stream>>>(rpB, rpE, eidx,
                                                 (const unsigned*)(m1p + (size_t)N * 32),    b1 + 32, dinv, m1h, 16, N);

    k_layer2  <<<(N + 63) / 64, 256, 0, stream>>>(m1h, W2, dinv, m2p, N);
    k_gather32h<<<(N + 15) / 16, 256, 0, stream>>>(rpB, rpE, eidx, (const unsigned*)m2p,
                                                   (void*)h2p, N, b2, dinv, nullptr, nullptr, nullptr);

    k_gather32h<<<(N + 15) / 16, 256, 0, stream>>>(rpB, rpE, eidx, (const unsigned*)h2p,
                                                   (void*)gbf, N, nullptr, dinv, W3, b3, out);

    dim3 gout((N + 63) / 64, 6);
    k_out<<<gout, 256, 0, stream>>>(gbf, w3t, b3, out, N);
}

// Round 19
// 144.801 us; speedup vs baseline: 1.0615x; 1.0615x over previous
//
#include <hip/hip_runtime.h>

#define F_IN  384
#define EPB   4096   // edges per block, pass 1
#define NBINS 256    // dsts per coarse bucket
#define BCAP  10240  // eidx region stride per bucket (avg 8163, ~20-sigma margin)
#define SDS   208    // segdesc row stride (u16 entries), >= NBK+1
#define WTBLK 144    // trailing k_p1 blocks doing weight transpose (36864/256)

typedef __attribute__((ext_vector_type(8))) short short8v;   // bf16x8 MFMA fragment
typedef __attribute__((ext_vector_type(4))) float f32x4;     // MFMA accumulator

// bf16 helpers (RNE), no header-type dependence
__device__ __forceinline__ unsigned short f2bf(float f) {
    unsigned u = __float_as_uint(f);
    return (unsigned short)((u + 0x7FFFu + ((u >> 16) & 1u)) >> 16);
}
__device__ __forceinline__ float bflo(unsigned u) { return __uint_as_float(u << 16); }
__device__ __forceinline__ float bfhi(unsigned u) { return __uint_as_float(u & 0xFFFF0000u); }

// ---------------- pass 1: coarse bucket partition + (tail blocks) weight transpose ----------------

__launch_bounds__(256)
__global__ void k_p1(const int* __restrict__ ei, int E, int NBK, int NB1,
                     unsigned* __restrict__ packed, unsigned short* __restrict__ segdesc,
                     const float* __restrict__ W1, const float* __restrict__ W3,
                     unsigned short* __restrict__ w1t, unsigned short* __restrict__ w3t) {
    __shared__ unsigned sin[EPB];
    __shared__ unsigned sout[EPB];
    __shared__ int hist[257], cur[256], excl[257];
    const int t = threadIdx.x;

    if (blockIdx.x >= NB1) {   // weight-transpose tail blocks
        int idx = (blockIdx.x - NB1) * 256 + t;
        if (idx < 384 * 64) {                 // W1: [k=384][col=64] -> w1t[col][k]
            int k = idx >> 6, col = idx & 63;
            w1t[(size_t)col * 384 + k] = f2bf(W1[idx]);
        } else {
            int j = idx - 384 * 64;           // W3 cols 0..383: [k=32][col=385] -> w3t[col][k]
            if (j < 384 * 32) {
                int col = j >> 5, k = j & 31;
                w3t[(size_t)col * 32 + k] = f2bf(W3[(size_t)k * 385 + col]);
            }
        }
        return;
    }

    const int e0 = blockIdx.x * EPB;
    const int cnt = min(EPB, E - e0);

    if (t < 256) { hist[t] = 0; cur[t] = 0; }
    if (t == 0) hist[256] = 0;
    __syncthreads();

    for (int i = t; i < cnt; i += 256) {
        int s = ei[e0 + i];
        int d = ei[E + e0 + i];
        sin[i] = ((unsigned)d << 16) | (unsigned)s;   // N < 65536 for both
        atomicAdd(&hist[d >> 8], 1);
    }
    __syncthreads();

    if (t < 64) {  // wave 0: exclusive scan of hist[0..NBK)
        int carry = 0;
        for (int c = 0; c * 64 < NBK; ++c) {
            int idx = c * 64 + t;
            int v = (idx < NBK) ? hist[idx] : 0;
            int x = v;
#pragma unroll
            for (int d = 1; d < 64; d <<= 1) { int y = __shfl_up(x, d, 64); if (t >= d) x += y; }
            if (idx < NBK) excl[idx] = carry + x - v;
            carry += __shfl(x, 63, 64);
        }
        if (t == 0) excl[NBK] = carry;   // == cnt
    }
    __syncthreads();

    for (int i = t; i < cnt; i += 256) {
        unsigned v = sin[i];
        int b = v >> 24;                 // dst >> 8
        int pos = excl[b] + atomicAdd(&cur[b], 1);   // LDS atomic (fast)
        sout[pos] = v;
    }
    __syncthreads();

    for (int i = t; i < cnt; i += 256) packed[(size_t)e0 + i] = sout[i];   // coalesced
    for (int i = t; i <= NBK; i += 256) segdesc[(size_t)blockIdx.x * SDS + i] = (unsigned short)excl[i];
}

// ---------------- pass 2: per-bucket exact CSR (rpB/rpE/dinv/eidx), all in LDS ----------------

__launch_bounds__(256)
__global__ void k_p2(const unsigned* __restrict__ packed, const unsigned short* __restrict__ segdesc,
                     int NB1, unsigned short* __restrict__ eidx,
                     int* __restrict__ rpB, int* __restrict__ rpE,
                     float* __restrict__ dinv, int N) {
    __shared__ unsigned ev[BCAP];
    __shared__ unsigned short se[BCAP];
    __shared__ int lenS[512], offS[513], srcS[512];
    __shared__ int hist[NBINS], cur[NBINS], excl[NBINS + 1];
    const int t = threadIdx.x;
    const int b = blockIdx.x;

    if (t < NBINS) { hist[t] = 0; cur[t] = 0; }
    for (int blk = t; blk < NB1; blk += 256) {
        int s0 = segdesc[(size_t)blk * SDS + b];
        int s1 = segdesc[(size_t)blk * SDS + b + 1];
        lenS[blk] = s1 - s0;
        srcS[blk] = s0;
    }
    __syncthreads();

    if (t < 64) {  // wave 0: exclusive scan of lenS[0..NB1)
        int carry = 0;
        for (int c = 0; c * 64 < NB1; ++c) {
            int idx = c * 64 + t;
            int v = (idx < NB1) ? lenS[idx] : 0;
            int x = v;
#pragma unroll
            for (int d = 1; d < 64; d <<= 1) { int y = __shfl_up(x, d, 64); if (t >= d) x += y; }
            if (idx < NB1) offS[idx] = carry + x - v;
            carry += __shfl(x, 63, 64);
        }
        if (t == 0) offS[NB1 < 512 ? NB1 : 512] = carry;
    }
    __syncthreads();
    const int total = min(offS[NB1 < 512 ? NB1 : 512], BCAP);

    for (int blk = t; blk < NB1; blk += 256) {
        int l = lenS[blk], o = offS[blk];
        if (o + l > BCAP) l = max(0, BCAP - o);
        const unsigned* sp = packed + (size_t)blk * EPB + srcS[blk];
        for (int j = 0; j < l; ++j) ev[o + j] = sp[j];
    }
    __syncthreads();

    for (int i = t; i < total; i += 256) atomicAdd(&hist[(ev[i] >> 16) & 0xFF], 1);
    __syncthreads();

    if (t < 64) {  // wave 0: exclusive scan of hist[0..256)
        int carry = 0;
#pragma unroll
        for (int c = 0; c < 4; ++c) {
            int idx = c * 64 + t;
            int v = hist[idx];
            int x = v;
#pragma unroll
            for (int d = 1; d < 64; d <<= 1) { int y = __shfl_up(x, d, 64); if (t >= d) x += y; }
            excl[idx] = carry + x - v;
            carry += __shfl(x, 63, 64);
        }
        if (t == 0) excl[NBINS] = carry;
    }
    __syncthreads();

    if (t < NBINS) {
        int d = b * NBINS + t;
        if (d < N) {
            int c = hist[t];
            int base = b * BCAP + excl[t];
            rpB[d] = base;
            rpE[d] = base + c;
            dinv[d] = rsqrtf((float)(c + 1));   // +1 self-loop
        }
    }
    for (int i = t; i < total; i += 256) {
        unsigned v = ev[i];
        int l = (v >> 16) & 0xFF;
        int p = excl[l] + atomicAdd(&cur[l], 1);
        se[p] = (unsigned short)(v & 0xFFFF);
    }
    __syncthreads();
    for (int i = t; i < total; i += 256) eidx[(size_t)b * BCAP + i] = se[i];
}

// ---------------- GEMM1 (MFMA): m1p = bf16((x @ W1) * dinv), reg-double-buffered stage ----------------

__launch_bounds__(256)
__global__ void k_gemm1(const float* __restrict__ x, const unsigned short* __restrict__ w1t,
                        const float* __restrict__ dinv,
                        unsigned short* __restrict__ m1p, int N) {
    __shared__ __align__(16) unsigned short xb[32][136];
    const int t    = threadIdx.x;
    const int lane = t & 63;
    const int wv   = t >> 6;        // wave id 0..3 -> col strip
    const int lr   = lane & 15;     // fragment row (A) / col (B)
    const int kg   = lane >> 4;     // k-group 0..3
    const int row0 = blockIdx.x * 32;
    const int col  = (wv << 4) + lr;

    short8v bf[12];
    const unsigned short* wcol = w1t + (size_t)col * 384 + (kg << 3);
#pragma unroll
    for (int c = 0; c < 12; c++)
        bf[c] = *reinterpret_cast<const short8v*>(&wcol[c * 32]);

    int sr[2], sk[2];
    const float* sp[2];
    bool sv[2];
#pragma unroll
    for (int i = 0; i < 2; i++) {
        int g = t + i * 256;
        sr[i] = g >> 4;
        sk[i] = (g & 15) << 3;
        int row = row0 + sr[i];
        sv[i] = (row < N);
        sp[i] = x + (size_t)row * F_IN + sk[i];
    }

    float4 preA0, preA1, preB0, preB1;
    preA0 = sv[0] ? *reinterpret_cast<const float4*>(sp[0])     : make_float4(0, 0, 0, 0);
    preA1 = sv[0] ? *reinterpret_cast<const float4*>(sp[0] + 4) : make_float4(0, 0, 0, 0);
    preB0 = sv[1] ? *reinterpret_cast<const float4*>(sp[1])     : make_float4(0, 0, 0, 0);
    preB1 = sv[1] ? *reinterpret_cast<const float4*>(sp[1] + 4) : make_float4(0, 0, 0, 0);

    f32x4 acc0 = (f32x4){0.f, 0.f, 0.f, 0.f};
    f32x4 acc1 = (f32x4){0.f, 0.f, 0.f, 0.f};

    for (int k0 = 0; k0 < F_IN; k0 += 128) {
        __syncthreads();
        {
            short8v p;
            p[0] = (short)f2bf(preA0.x); p[1] = (short)f2bf(preA0.y);
            p[2] = (short)f2bf(preA0.z); p[3] = (short)f2bf(preA0.w);
            p[4] = (short)f2bf(preA1.x); p[5] = (short)f2bf(preA1.y);
            p[6] = (short)f2bf(preA1.z); p[7] = (short)f2bf(preA1.w);
            *reinterpret_cast<short8v*>(&xb[sr[0]][sk[0]]) = p;
            p[0] = (short)f2bf(preB0.x); p[1] = (short)f2bf(preB0.y);
            p[2] = (short)f2bf(preB0.z); p[3] = (short)f2bf(preB0.w);
            p[4] = (short)f2bf(preB1.x); p[5] = (short)f2bf(preB1.y);
            p[6] = (short)f2bf(preB1.z); p[7] = (short)f2bf(preB1.w);
            *reinterpret_cast<short8v*>(&xb[sr[1]][sk[1]]) = p;
        }
        if (k0 + 128 < F_IN) {
            const float* q0 = sp[0] + k0 + 128;
            const float* q1 = sp[1] + k0 + 128;
            preA0 = sv[0] ? *reinterpret_cast<const float4*>(q0)     : make_float4(0, 0, 0, 0);
            preA1 = sv[0] ? *reinterpret_cast<const float4*>(q0 + 4) : make_float4(0, 0, 0, 0);
            preB0 = sv[1] ? *reinterpret_cast<const float4*>(q1)     : make_float4(0, 0, 0, 0);
            preB1 = sv[1] ? *reinterpret_cast<const float4*>(q1 + 4) : make_float4(0, 0, 0, 0);
        }
        __syncthreads();

#pragma unroll
        for (int kk = 0; kk < 4; kk++) {
            const int c = (k0 >> 5) + kk;
            short8v a0 = *reinterpret_cast<const short8v*>(&xb[lr][(kk << 5) + (kg << 3)]);
            short8v a1 = *reinterpret_cast<const short8v*>(&xb[16 + lr][(kk << 5) + (kg << 3)]);
            acc0 = __builtin_amdgcn_mfma_f32_16x16x32_bf16(a0, bf[c], acc0, 0, 0, 0);
            acc1 = __builtin_amdgcn_mfma_f32_16x16x32_bf16(a1, bf[c], acc1, 0, 0, 0);
        }
    }

    const size_t hbase = (size_t)(col >> 5) * ((size_t)N * 32) + (col & 31);
#pragma unroll
    for (int i = 0; i < 4; i++) {
        int rowA = row0 + (kg << 2) + i;
        if (rowA < N) m1p[hbase + (size_t)rowA * 32] = f2bf(acc0[i] * dinv[rowA]);
        int rowB = row0 + 16 + (kg << 2) + i;
        if (rowB < N) m1p[hbase + (size_t)rowB * 32] = f2bf(acc1[i] * dinv[rowB]);
    }
}

// ---------------- gather layer-1, one feature-half: m1h half = bf16(relu(s*agg + b1h)) ----------------

__launch_bounds__(256)
__global__ void k_g64half(const int* __restrict__ rpB, const int* __restrict__ rpE,
                          const unsigned short* __restrict__ eidx,
                          const unsigned* __restrict__ msg,   // [N][16] packed bf16 pairs (half h)
                          const float* __restrict__ b1h,
                          const float* __restrict__ dinv,
                          unsigned* __restrict__ m1h,
                          int houtoff, int N) {
    int w = blockIdx.x * 16 + (threadIdx.x >> 4);
    if (w >= N) return;
    int f = threadIdx.x & 15;
    int i = rpB[w], e = rpE[w];
    unsigned u = msg[(size_t)w * 16 + f];           // self-loop
    float l0 = bflo(u), h0 = bfhi(u);
    float l1 = 0.f, h1 = 0.f, l2 = 0.f, h2 = 0.f, l3 = 0.f, h3 = 0.f;
    float l4 = 0.f, h4 = 0.f, l5 = 0.f, h5 = 0.f, l6 = 0.f, h6 = 0.f, l7 = 0.f, h7 = 0.f;
    for (; i + 8 <= e; i += 8) {
        unsigned u0 = msg[(size_t)eidx[i]     * 16 + f];
        unsigned u1 = msg[(size_t)eidx[i + 1] * 16 + f];
        unsigned u2 = msg[(size_t)eidx[i + 2] * 16 + f];
        unsigned u3 = msg[(size_t)eidx[i + 3] * 16 + f];
        unsigned u4 = msg[(size_t)eidx[i + 4] * 16 + f];
        unsigned u5 = msg[(size_t)eidx[i + 5] * 16 + f];
        unsigned u6 = msg[(size_t)eidx[i + 6] * 16 + f];
        unsigned u7 = msg[(size_t)eidx[i + 7] * 16 + f];
        l0 += bflo(u0); h0 += bfhi(u0);  l1 += bflo(u1); h1 += bfhi(u1);
        l2 += bflo(u2); h2 += bfhi(u2);  l3 += bflo(u3); h3 += bfhi(u3);
        l4 += bflo(u4); h4 += bfhi(u4);  l5 += bflo(u5); h5 += bfhi(u5);
        l6 += bflo(u6); h6 += bfhi(u6);  l7 += bflo(u7); h7 += bfhi(u7);
    }
    for (; i + 4 <= e; i += 4) {
        unsigned u0 = msg[(size_t)eidx[i]     * 16 + f];
        unsigned u1 = msg[(size_t)eidx[i + 1] * 16 + f];
        unsigned u2 = msg[(size_t)eidx[i + 2] * 16 + f];
        unsigned u3 = msg[(size_t)eidx[i + 3] * 16 + f];
        l0 += bflo(u0); h0 += bfhi(u0);  l1 += bflo(u1); h1 += bfhi(u1);
        l2 += bflo(u2); h2 += bfhi(u2);  l3 += bflo(u3); h3 += bfhi(u3);
    }
    for (; i < e; i++) {
        unsigned u0 = msg[(size_t)eidx[i] * 16 + f];
        l0 += bflo(u0); h0 += bfhi(u0);
    }
    float suml = ((l0 + l1) + (l2 + l3)) + ((l4 + l5) + (l6 + l7));
    float sumh = ((h0 + h1) + (h2 + h3)) + ((h4 + h5) + (h6 + h7));
    float s = dinv[w];
    float hl = fmaxf(suml * s + b1h[(f << 1)], 0.f);
    float hh = fmaxf(sumh * s + b1h[(f << 1) + 1], 0.f);
    m1h[(size_t)w * 32 + houtoff + f] = (unsigned)f2bf(hl) | ((unsigned)f2bf(hh) << 16);
}

// ---------------- CSR gather, 32 bf16 features, mid-layer epilogue (bias path only) ----------------

__launch_bounds__(256)
__global__ void k_gather32h(const int* __restrict__ rpB, const int* __restrict__ rpE,
                            const unsigned short* __restrict__ eidx,
                            const unsigned* __restrict__ msg,   // [N][16] packed bf16 pairs
                            unsigned* __restrict__ outp, int N,
                            const float* __restrict__ bias, const float* __restrict__ dinv) {
    int w = blockIdx.x * 16 + (threadIdx.x >> 4);
    if (w >= N) return;
    int f = threadIdx.x & 15;
    int i = rpB[w], e = rpE[w];
    unsigned u = msg[(size_t)w * 16 + f];           // self-loop
    float l0 = bflo(u), h0 = bfhi(u);
    float l1 = 0.f, h1 = 0.f, l2 = 0.f, h2 = 0.f, l3 = 0.f, h3 = 0.f;
    float l4 = 0.f, h4 = 0.f, l5 = 0.f, h5 = 0.f, l6 = 0.f, h6 = 0.f, l7 = 0.f, h7 = 0.f;
    for (; i + 8 <= e; i += 8) {
        unsigned u0 = msg[(size_t)eidx[i]     * 16 + f];
        unsigned u1 = msg[(size_t)eidx[i + 1] * 16 + f];
        unsigned u2 = msg[(size_t)eidx[i + 2] * 16 + f];
        unsigned u3 = msg[(size_t)eidx[i + 3] * 16 + f];
        unsigned u4 = msg[(size_t)eidx[i + 4] * 16 + f];
        unsigned u5 = msg[(size_t)eidx[i + 5] * 16 + f];
        unsigned u6 = msg[(size_t)eidx[i + 6] * 16 + f];
        unsigned u7 = msg[(size_t)eidx[i + 7] * 16 + f];
        l0 += bflo(u0); h0 += bfhi(u0);  l1 += bflo(u1); h1 += bfhi(u1);
        l2 += bflo(u2); h2 += bfhi(u2);  l3 += bflo(u3); h3 += bfhi(u3);
        l4 += bflo(u4); h4 += bfhi(u4);  l5 += bflo(u5); h5 += bfhi(u5);
        l6 += bflo(u6); h6 += bfhi(u6);  l7 += bflo(u7); h7 += bfhi(u7);
    }
    for (; i + 4 <= e; i += 4) {
        unsigned u0 = msg[(size_t)eidx[i]     * 16 + f];
        unsigned u1 = msg[(size_t)eidx[i + 1] * 16 + f];
        unsigned u2 = msg[(size_t)eidx[i + 2] * 16 + f];
        unsigned u3 = msg[(size_t)eidx[i + 3] * 16 + f];
        l0 += bflo(u0); h0 += bfhi(u0);  l1 += bflo(u1); h1 += bfhi(u1);
        l2 += bflo(u2); h2 += bfhi(u2);  l3 += bflo(u3); h3 += bfhi(u3);
    }
    for (; i < e; i++) {
        unsigned u0 = msg[(size_t)eidx[i] * 16 + f];
        l0 += bflo(u0); h0 += bfhi(u0);
    }
    float rl = ((l0 + l1) + (l2 + l3)) + ((l4 + l5) + (l6 + l7));
    float rh = ((h0 + h1) + (h2 + h3)) + ((h4 + h5) + (h6 + h7));
    float s = dinv[w];
    rl = fmaxf(rl * s + bias[(f << 1)], 0.f) * s;
    rh = fmaxf(rh * s + bias[(f << 1) + 1], 0.f) * s;
    outp[(size_t)w * 16 + f] = (unsigned)f2bf(rl) | ((unsigned)f2bf(rh) << 16);
}

// ---------------- layer2 (MFMA, LDS-free): m2p = bf16((m1h @ W2) * s) ----------------

__launch_bounds__(256)
__global__ void k_layer2(const unsigned* __restrict__ m1h, const float* __restrict__ W2,
                         const float* __restrict__ dinv,
                         unsigned short* __restrict__ m2p, int N) {
    const int t    = threadIdx.x;
    const int lane = t & 63;
    const int wv   = t >> 6;
    const int lr   = lane & 15;
    const int kg   = lane >> 4;
    const int row0 = blockIdx.x * 64 + (wv << 4);

    short8v b00, b01, b10, b11;
#pragma unroll
    for (int j = 0; j < 8; j++) {
        int k = (kg << 3) + j;
        b00[j] = (short)f2bf(W2[(size_t)k * 32 + lr]);
        b01[j] = (short)f2bf(W2[(size_t)k * 32 + 16 + lr]);
        b10[j] = (short)f2bf(W2[(size_t)(32 + k) * 32 + lr]);
        b11[j] = (short)f2bf(W2[(size_t)(32 + k) * 32 + 16 + lr]);
    }

    int arow = row0 + lr;
    short8v a0 = (short8v){0, 0, 0, 0, 0, 0, 0, 0};
    short8v a1 = (short8v){0, 0, 0, 0, 0, 0, 0, 0};
    if (arow < N) {
        a0 = *reinterpret_cast<const short8v*>(&m1h[(size_t)arow * 32 + (kg << 2)]);
        a1 = *reinterpret_cast<const short8v*>(&m1h[(size_t)arow * 32 + 16 + (kg << 2)]);
    }

    f32x4 accA = (f32x4){0.f, 0.f, 0.f, 0.f};
    f32x4 accB = (f32x4){0.f, 0.f, 0.f, 0.f};
    accA = __builtin_amdgcn_mfma_f32_16x16x32_bf16(a0, b00, accA, 0, 0, 0);
    accA = __builtin_amdgcn_mfma_f32_16x16x32_bf16(a1, b10, accA, 0, 0, 0);
    accB = __builtin_amdgcn_mfma_f32_16x16x32_bf16(a0, b01, accB, 0, 0, 0);
    accB = __builtin_amdgcn_mfma_f32_16x16x32_bf16(a1, b11, accB, 0, 0, 0);

#pragma unroll
    for (int i = 0; i < 4; i++) {
        int row = row0 + (kg << 2) + i;
        if (row < N) {
            float s = dinv[row];
            m2p[(size_t)row * 32 + lr]      = f2bf(accA[i] * s);
            m2p[(size_t)row * 32 + 16 + lr] = f2bf(accB[i] * s);
        }
    }
}

// ---------------- FUSED final gather + out GEMM ----------------
// 64 nodes/block, 256 threads. Phase 1: 4 lanes/node gather uint4 rows of h2p
// (L2-resident), scale by dinv, pack g into 4KB LDS, fused col-384 GEMV (f32).
// Phase 2: k_out body in-block: 6 col-strips x 4 row-blocks of 16x16x32 MFMA
// from LDS g + w3t, bias + sigmoid(col 0), coalesced-enough scalar stores.

__launch_bounds__(256)
__global__ void k_g32out(const int* __restrict__ rpB, const int* __restrict__ rpE,
                         const unsigned short* __restrict__ eidx,
                         const uint4* __restrict__ msg,     // h2p as [N][4] uint4
                         const float* __restrict__ dinv,
                         const unsigned short* __restrict__ w3t,
                         const float* __restrict__ W3, const float* __restrict__ b3,
                         float* __restrict__ out, int N) {
    __shared__ unsigned g[64][16];
    const int t    = threadIdx.x;
    const int row0 = blockIdx.x * 64;
    const int wn   = t >> 2;        // node-in-block 0..63
    const int q    = t & 3;         // quarter of the 16-u32 row
    const int w    = row0 + wn;

    if (w < N) {
        int i = rpB[w], e = rpE[w];
        uint4 u = msg[(size_t)w * 4 + q];   // self-loop
        float a0 = bflo(u.x), a1 = bfhi(u.x), a2 = bflo(u.y), a3 = bfhi(u.y);
        float a4 = bflo(u.z), a5 = bfhi(u.z), a6 = bflo(u.w), a7 = bfhi(u.w);
        float c0 = 0.f, c1 = 0.f, c2 = 0.f, c3 = 0.f, c4 = 0.f, c5 = 0.f, c6 = 0.f, c7 = 0.f;
        for (; i + 4 <= e; i += 4) {
            uint4 v0 = msg[(size_t)eidx[i]     * 4 + q];
            uint4 v1 = msg[(size_t)eidx[i + 1] * 4 + q];
            uint4 v2 = msg[(size_t)eidx[i + 2] * 4 + q];
            uint4 v3 = msg[(size_t)eidx[i + 3] * 4 + q];
            a0 += bflo(v0.x); a1 += bfhi(v0.x); a2 += bflo(v0.y); a3 += bfhi(v0.y);
            a4 += bflo(v0.z); a5 += bfhi(v0.z); a6 += bflo(v0.w); a7 += bfhi(v0.w);
            c0 += bflo(v1.x); c1 += bfhi(v1.x); c2 += bflo(v1.y); c3 += bfhi(v1.y);
            c4 += bflo(v1.z); c5 += bfhi(v1.z); c6 += bflo(v1.w); c7 += bfhi(v1.w);
            a0 += bflo(v2.x); a1 += bfhi(v2.x); a2 += bflo(v2.y); a3 += bfhi(v2.y);
            a4 += bflo(v2.z); a5 += bfhi(v2.z); a6 += bflo(v2.w); a7 += bfhi(v2.w);
            c0 += bflo(v3.x); c1 += bfhi(v3.x); c2 += bflo(v3.y); c3 += bfhi(v3.y);
            c4 += bflo(v3.z); c5 += bfhi(v3.z); c6 += bflo(v3.w); c7 += bfhi(v3.w);
        }
        for (; i < e; i++) {
            uint4 v0 = msg[(size_t)eidx[i] * 4 + q];
            a0 += bflo(v0.x); a1 += bfhi(v0.x); a2 += bflo(v0.y); a3 += bfhi(v0.y);
            a4 += bflo(v0.z); a5 += bfhi(v0.z); a6 += bflo(v0.w); a7 += bfhi(v0.w);
        }
        float s = dinv[w];
        float g0 = (a0 + c0) * s, g1 = (a1 + c1) * s, g2 = (a2 + c2) * s, g3 = (a3 + c3) * s;
        float g4 = (a4 + c4) * s, g5 = (a5 + c5) * s, g6 = (a6 + c6) * s, g7 = (a7 + c7) * s;
        g[wn][q * 4 + 0] = (unsigned)f2bf(g0) | ((unsigned)f2bf(g1) << 16);
        g[wn][q * 4 + 1] = (unsigned)f2bf(g2) | ((unsigned)f2bf(g3) << 16);
        g[wn][q * 4 + 2] = (unsigned)f2bf(g4) | ((unsigned)f2bf(g5) << 16);
        g[wn][q * 4 + 3] = (unsigned)f2bf(g6) | ((unsigned)f2bf(g7) << 16);
        // fused column 384 (f32 precision): k = 8q..8q+7
        const float* wc = W3 + (size_t)(8 * q) * 385 + 384;
        float p = g0 * wc[0] + g1 * wc[385] + g2 * wc[2 * 385] + g3 * wc[3 * 385]
                + g4 * wc[4 * 385] + g5 * wc[5 * 385] + g6 * wc[6 * 385] + g7 * wc[7 * 385];
        p += __shfl_xor(p, 1, 64);
        p += __shfl_xor(p, 2, 64);
        if (q == 0) out[(size_t)w * 385 + 384] = p + b3[384];
    } else {
        g[wn][q * 4 + 0] = 0; g[wn][q * 4 + 1] = 0;
        g[wn][q * 4 + 2] = 0; g[wn][q * 4 + 3] = 0;
    }
    __syncthreads();

    const int lane = t & 63;
    const int wv   = t >> 6;
    const int lr   = lane & 15;
    const int kg   = lane >> 4;
#pragma unroll
    for (int y = 0; y < 6; y++) {
        int col = y * 64 + (wv << 4) + lr;   // < 384
        short8v bfrag = *reinterpret_cast<const short8v*>(&w3t[(size_t)col * 32 + (kg << 3)]);
        float bias = b3[col];
#pragma unroll
        for (int rb = 0; rb < 4; rb++) {
            short8v afrag = *reinterpret_cast<const short8v*>(&g[(rb << 4) + lr][kg << 2]);
            f32x4 acc = (f32x4){0.f, 0.f, 0.f, 0.f};
            acc = __builtin_amdgcn_mfma_f32_16x16x32_bf16(afrag, bfrag, acc, 0, 0, 0);
#pragma unroll
            for (int i = 0; i < 4; i++) {
                int row = row0 + (rb << 4) + (kg << 2) + i;
                if (row < N) {
                    float v = acc[i] + bias;
                    if (col == 0) v = 1.0f / (1.0f + expf(-v));
                    out[(size_t)row * 385 + col] = v;
                }
            }
        }
    }
}

extern "C" void kernel_launch(void* const* d_in, const int* in_sizes, int n_in,
                              void* d_out, int out_size, void* d_ws, size_t ws_size,
                              hipStream_t stream) {
    const float* x  = (const float*)d_in[0];
    const int*   ei = (const int*)d_in[1];
    const float* W1 = (const float*)d_in[2];
    const float* b1 = (const float*)d_in[3];
    const float* W2 = (const float*)d_in[4];
    const float* b2 = (const float*)d_in[5];
    const float* W3 = (const float*)d_in[6];
    const float* b3 = (const float*)d_in[7];
    float* out = (float*)d_out;

    const int N = in_sizes[0] / F_IN;   // 50000
    const int E = in_sizes[1] / 2;      // 1600000
    const int NB1 = (E + EPB - 1) / EPB;       // 391 pass-1 blocks
    const int NBK = (N + NBINS - 1) / NBINS;   // 196 coarse buckets

    float* ws   = (float*)d_ws;
    float* dinv = ws;
    float* bufA = ws + N;
    float* bufB = bufA + (size_t)64 * N;
    int*   rpB  = (int*)(bufB + (size_t)64 * N);
    int*   rpE  = rpB + N;
    unsigned short* eidx    = (unsigned short*)(rpE + N);
    unsigned short* segdesc = eidx + (size_t)NBK * BCAP;
    unsigned short* w1t     = segdesc + (size_t)NB1 * SDS;   // [64][384] bf16
    unsigned short* w3t     = w1t + (size_t)64 * 384;        // [384][32] bf16

    unsigned* packed = (unsigned*)bufA;              // E u32; dead after k_p2
    unsigned short* m1p = (unsigned short*)bufA;     // [2][N][32] bf16 halves
    unsigned* m1h = (unsigned*)bufB;                 // [N][32] u32 packed bf16 h1
    unsigned short* m2p = (unsigned short*)bufA;     // [N,32] bf16 (m1p dead)
    unsigned short* h2p = (unsigned short*)bufB;     // [N,32] bf16 (m1h dead)

    k_p1<<<NB1 + WTBLK, 256, 0, stream>>>(ei, E, NBK, NB1, packed, segdesc, W1, W3, w1t, w3t);
    k_p2<<<NBK, 256, 0, stream>>>(packed, segdesc, NB1, eidx, rpB, rpE, dinv, N);

    k_gemm1  <<<(N + 31) / 32, 256, 0, stream>>>(x, w1t, dinv, m1p, N);
    k_g64half<<<(N + 15) / 16, 256, 0, stream>>>(rpB, rpE, eidx,
                                                 (const unsigned*)m1p,                    b1,      dinv, m1h,  0, N);
    k_g64half<<<(N + 15) / 16, 256, 0, stream>>>(rpB, rpE, eidx,
                                                 (const unsigned*)(m1p + (size_t)N * 32), b1 + 32, dinv, m1h, 16, N);

    k_layer2  <<<(N + 63) / 64, 256, 0, stream>>>(m1h, W2, dinv, m2p, N);
    k_gather32h<<<(N + 15) / 16, 256, 0, stream>>>(rpB, rpE, eidx, (const unsigned*)m2p,
                                                   (unsigned*)h2p, N, b2, dinv);

    k_g32out<<<(N + 63) / 64, 256, 0, stream>>>(rpB, rpE, eidx, (const uint4*)h2p, dinv,
                                                w3t, W3, b3, out, N);
}